// Round 12
// baseline (139.814 us; speedup 1.0000x reference)
//
#include <hip/hip_runtime.h>

// FixedActionDecoder: sims = (X/||x||) @ (A/||a||cols); segment-max over
// ACTION_INDEX=[0,0,0,0,1,1,1,1,1,2,3]; argmax; one-hot.
// Row-norm of X is argmax-invariant -> skipped.
//
// r12 = r9 EXACT (best measured: 77.8us) + r8's proven work-steal:
//  - decode: half-row phases (8 lanes/row -> full 128B-line staging
//    requests), 128-row wave tiles, 2 rows/lane, stride-36 LDS rows
//    (measured 0 bank conflicts), W broadcast as d-major quads (11 uniform
//    ds_read_b128 per chunk), 4 blocks/CU = 8 waves/CU.
//  - steal: first tile static (= global wave id), overflow tiles via
//    atomicAdd on a d_ws counter (hipMemsetAsync reset; r7/r8-proven
//    capture-safe). Kills the 3-vs-4-tile quantization tail (~5%).
//  - prep: parallel (~2us); repair: SEPARATE kernel (r9's). r11 proved the
//    fused-repair branch catastrophic (decode 66->146us: __noinline__ call
//    in the hot loop wrecks scheduling); never fuse it again.
// Lessons: r2 (unroll 1 on uniform-table loops), r6 (no reg staging
// arrays), r3 (g_* never share d_ws with data), r5/r10 (DMA staging
// abandoned), r11 (no calls/branches in hot loop).
// Numerics: f32 pass + gap<TAU ballot -> f64 repair (validated every
// passing round; absmax 0).

#define NP 11
#define TAU 1e-3f
#define LROW 36  // LDS row stride (dwords): 32 data + 4 pad; 0-conflict (r11 PMC)

__device__ __align__(16) float g_W32[704];      // [(d>>2)*44 + p*4 + (d&3)]
__device__ double g_W64[704];                   // [d*11 + p]
__device__ unsigned long long g_bits[1 << 20];  // near-tie flags, 1 bit/row

// Parallel prep (~2us): thread d owns row d of A; column norms via LDS.
__global__ void prep(const float* __restrict__ A) {
    __shared__ double sq[64][NP + 1];
    __shared__ double sc[NP];
    const int d = threadIdx.x;  // 0..63
    double a[NP];
    #pragma unroll
    for (int p = 0; p < NP; ++p) {
        a[p] = (double)A[d * NP + p];
        sq[d][p] = a[p] * a[p];
    }
    __syncthreads();
    if (d < NP) {
        double ss = 0.0;
        #pragma unroll
        for (int r = 0; r < 64; ++r) ss += sq[r][d];
        sc[d] = 1.0 / fmax(sqrt(ss), 1e-8);
    }
    __syncthreads();
    #pragma unroll
    for (int p = 0; p < NP; ++p) {
        double w = a[p] * sc[p];
        g_W64[d * NP + p] = w;
        g_W32[(d >> 2) * 44 + p * 4 + (d & 3)] = (float)w;  // d-major quad
    }
}

__device__ __forceinline__ void argmax_gap(const float* s, int& idx, float& gap) {
    // Segment max per ACTION_INDEX = [0,0,0,0, 1,1,1,1,1, 2, 3]
    float m0 = fmaxf(fmaxf(s[0], s[1]), fmaxf(s[2], s[3]));
    float m1 = fmaxf(fmaxf(fmaxf(s[4], s[5]), s[6]), fmaxf(s[7], s[8]));
    float m2 = s[9], m3 = s[10];
    idx = 0; float best = m0;
    if (m1 > best) { best = m1; idx = 1; }
    if (m2 > best) { best = m2; idx = 2; }
    if (m3 > best) { best = m3; idx = 3; }
    float second = -3.4e38f;
    if (idx != 0) second = fmaxf(second, m0);
    if (idx != 1) second = fmaxf(second, m1);
    if (idx != 2) second = fmaxf(second, m2);
    if (idx != 3) second = fmaxf(second, m3);
    gap = best - second;
}

__global__ __launch_bounds__(128) void decode(const float* __restrict__ X,
                                              float* __restrict__ out,
                                              unsigned* __restrict__ ctr, int B) {
    __shared__ float xbuf[2][128][LROW];  // 36864 B, wave-private halves
    __shared__ float w_lds[704];          // 2816 B; total 39680 -> 4 blk/CU

    const int tid = threadIdx.x;
    const int lane = tid & 63;
    const int wv = tid >> 6;
    float(*buf)[LROW] = xbuf[wv];

    // Copy W into LDS: 176 float4s over 128 threads.
    for (int t = tid; t < 176; t += 128)
        reinterpret_cast<float4*>(w_lds)[t] =
            reinterpret_cast<const float4*>(g_W32)[t];
    __syncthreads();  // only block-wide sync; rest is wave-private

    const float4* X4 = reinterpret_cast<const float4*>(X);
    const int gwave = blockIdx.x * 2 + wv;
    const int nwaves = gridDim.x * 2;

    int t = gwave;  // first tile static; steal the rest (no t=0 herd)
    #pragma unroll 1
    for (;;) {
        const int base = t * 128;
        if (base >= B) break;

        float acc0[NP], acc1[NP];
        #pragma unroll
        for (int p = 0; p < NP; ++p) { acc0[p] = 0.0f; acc1[p] = 0.0f; }

        #pragma unroll
        for (int st = 0; st < 2; ++st) {  // d half: st*32 .. st*32+31
            // Stage 128 rows x 32 floats; instr i covers 8 FULL 128B lines
            // (8 lanes/row x 16 B contiguous).
            #pragma unroll
            for (int i = 0; i < 16; ++i) {
                int fid = i * 64 + lane;  // 0..1023
                int row = fid >> 3;       // 0..127
                int f = fid & 7;          // 0..7
                int r = base + row;
                if (r >= B) r = B - 1;    // tail clamp (dup read, harmless)
                float4 v = X4[(size_t)r * 16 + st * 8 + f];
                *reinterpret_cast<float4*>(&buf[row][f * 4]) = v;
            }
            __builtin_amdgcn_wave_barrier();  // wave-private buf: fence only

            // Per 4-d chunk: 2 lane b128 (X rows) + 11 uniform b128 (W
            // quads) + 88 v_fma_f32. unroll 1: W never bulk-hoisted (r2).
            #pragma unroll 1
            for (int kk = 0; kk < 8; ++kk) {
                const float* wrow = &w_lds[(st * 8 + kk) * 44];
                float4 x0 = *reinterpret_cast<const float4*>(&buf[lane][kk * 4]);
                float4 x1 = *reinterpret_cast<const float4*>(&buf[lane + 64][kk * 4]);
                #pragma unroll
                for (int p = 0; p < NP; ++p) {
                    float4 wq = *reinterpret_cast<const float4*>(&wrow[p * 4]);
                    float t0 = fmaf(x0.x, wq.x, acc0[p]);
                    t0 = fmaf(x0.y, wq.y, t0);
                    t0 = fmaf(x0.z, wq.z, t0);
                    acc0[p] = fmaf(x0.w, wq.w, t0);
                    float t1 = fmaf(x1.x, wq.x, acc1[p]);
                    t1 = fmaf(x1.y, wq.y, t1);
                    t1 = fmaf(x1.z, wq.z, t1);
                    acc1[p] = fmaf(x1.w, wq.w, t1);
                }
            }
            __builtin_amdgcn_wave_barrier();
        }

        int idx0, idx1; float gap0, gap1;
        argmax_gap(acc0, idx0, gap0);
        argmax_gap(acc1, idx1, gap1);

        unsigned long long m0 = __ballot(gap0 < TAU);
        unsigned long long m1 = __ballot(gap1 < TAU);
        if (lane == 0) {
            g_bits[(base >> 6) + 0] = m0;
            g_bits[(base >> 6) + 1] = m1;
        }

        int r0 = base + lane, r1 = base + 64 + lane;
        if (r0 < B) {
            float4 o;
            o.x = (idx0 == 0) ? 1.0f : 0.0f;
            o.y = (idx0 == 1) ? 1.0f : 0.0f;
            o.z = (idx0 == 2) ? 1.0f : 0.0f;
            o.w = (idx0 == 3) ? 1.0f : 0.0f;
            reinterpret_cast<float4*>(out)[r0] = o;
        }
        if (r1 < B) {
            float4 o;
            o.x = (idx1 == 0) ? 1.0f : 0.0f;
            o.y = (idx1 == 1) ? 1.0f : 0.0f;
            o.z = (idx1 == 2) ? 1.0f : 0.0f;
            o.w = (idx1 == 3) ? 1.0f : 0.0f;
            reinterpret_cast<float4*>(out)[r1] = o;
        }

        // Steal next tile (overflow range only; spread in time).
        int nt = 0;
        if (lane == 0) nt = (int)atomicAdd(ctr, 1u);
        t = __builtin_amdgcn_readfirstlane(nt) + nwaves;
    }
}

__global__ __launch_bounds__(256) void repair(const float* __restrict__ X,
                                              float* __restrict__ out, int B) {
    __shared__ double w64[704];  // copy of g_W64
    const int tid = threadIdx.x;
    for (int i = tid; i < 704; i += 256) w64[i] = g_W64[i];
    __syncthreads();

    const int nwords = (B + 63) >> 6;
    for (int t = blockIdx.x * blockDim.x + tid; t < nwords;
         t += gridDim.x * blockDim.x) {
        unsigned long long m = g_bits[t];
        while (m) {
            int b = __builtin_ctzll(m);
            m &= m - 1;
            int row = t * 64 + b;
            if (row >= B) continue;

            double s[NP];
            #pragma unroll
            for (int p = 0; p < NP; ++p) s[p] = 0.0;
            #pragma unroll 1
            for (int d = 0; d < 64; ++d) {
                double x = (double)X[(size_t)row * 64 + d];
                #pragma unroll
                for (int p = 0; p < NP; ++p)
                    s[p] = fma(x, w64[d * NP + p], s[p]);
            }

            double m0 = fmax(fmax(s[0], s[1]), fmax(s[2], s[3]));
            double m1 = fmax(fmax(fmax(s[4], s[5]), s[6]), fmax(s[7], s[8]));
            double m2 = s[9], m3 = s[10];
            int idx = 0; double best = m0;
            if (m1 > best) { best = m1; idx = 1; }
            if (m2 > best) { best = m2; idx = 2; }
            if (m3 > best) { best = m3; idx = 3; }

            float4 o;
            o.x = (idx == 0) ? 1.0f : 0.0f;
            o.y = (idx == 1) ? 1.0f : 0.0f;
            o.z = (idx == 2) ? 1.0f : 0.0f;
            o.w = (idx == 3) ? 1.0f : 0.0f;
            reinterpret_cast<float4*>(out)[row] = o;
        }
    }
}

extern "C" void kernel_launch(void* const* d_in, const int* in_sizes, int n_in,
                              void* d_out, int out_size, void* d_ws, size_t ws_size,
                              hipStream_t stream) {
    const float* X = (const float*)d_in[0];
    const float* A = (const float*)d_in[1];
    float* out = (float*)d_out;
    const int B = in_sizes[0] / 64;

    hipMemsetAsync(d_ws, 0, 4, stream);  // steal counter reset (capture-safe)
    hipLaunchKernelGGL(prep, dim3(1), dim3(64), 0, stream, A);
    hipLaunchKernelGGL(decode, dim3(1024), dim3(128), 0, stream,
                       X, out, (unsigned*)d_ws, B);
    hipLaunchKernelGGL(repair, dim3(128), dim3(256), 0, stream, X, out, B);
}

// Round 13
// 78.653 us; speedup vs baseline: 1.7776x; 1.7776x over previous
//
#include <hip/hip_runtime.h>

// FixedActionDecoder: sims = (X/||x||) @ (A/||a||cols); segment-max over
// ACTION_INDEX=[0,0,0,0,1,1,1,1,1,2,3]; argmax; one-hot.
// Row-norm of X is argmax-invariant -> skipped.
//
// r13 = r9 EXACT (measured best: 77.8us). All deviations tried and
// convicted:
//  - DMA global_load_lds staging: r5 (W s_load chains), r10 (1 wave/SIMD +
//    stores trapped in vmcnt queue) -> stall-bound, 100-125us.
//  - register staging arrays: r6 -> scratch spill, 250MB WRITE_SIZE, 201us.
//  - quarter-row phases: r7/r8 -> 128B-line splits, ~28% over-fetch.
//  - fused repair branch in hot loop: r11 -> decode 66->146us.
//  - work-steal atomics: r12 -> vmcnt(0) drain + same-address atomic
//    serialization at every tile boundary, 139us.
// Decode structure: half-row phases (8 lanes/row -> every staging request
// covers a full 128B line), 128-row wave tiles, 2 rows/lane, stride-36 LDS
// rows (PMC-verified 0 bank conflicts), W broadcast as d-major quads
// (11 uniform ds_read_b128 per chunk), 4 blocks/CU = 8 waves/CU.
// Numerics: f32 pass + gap<TAU ballot -> f64 repair kernel
// (r1/r2-validated; absmax 0 in every passing round).

#define NP 11
#define TAU 1e-3f
#define LROW 36  // LDS row stride (dwords): 32 data + 4 pad (verified 0-conflict)

__device__ __align__(16) float g_W32[704];      // [(d>>2)*44 + p*4 + (d&3)]
__device__ double g_W64[704];                   // [d*11 + p]
__device__ unsigned long long g_bits[1 << 20];  // near-tie flags, 1 bit/row

// Parallel prep (~2us): thread d owns row d of A; column norms via LDS.
__global__ void prep(const float* __restrict__ A) {
    __shared__ double sq[64][NP + 1];  // +1 pad
    __shared__ double sc[NP];
    const int d = threadIdx.x;  // 0..63
    double a[NP];
    #pragma unroll
    for (int p = 0; p < NP; ++p) {
        a[p] = (double)A[d * NP + p];
        sq[d][p] = a[p] * a[p];
    }
    __syncthreads();
    if (d < NP) {
        double ss = 0.0;
        #pragma unroll
        for (int r = 0; r < 64; ++r) ss += sq[r][d];
        sc[d] = 1.0 / fmax(sqrt(ss), 1e-8);
    }
    __syncthreads();
    #pragma unroll
    for (int p = 0; p < NP; ++p) {
        double w = a[p] * sc[p];
        g_W64[d * NP + p] = w;
        g_W32[(d >> 2) * 44 + p * 4 + (d & 3)] = (float)w;  // d-major quad
    }
}

__device__ __forceinline__ void argmax_gap(const float* s, int& idx, float& gap) {
    // Segment max per ACTION_INDEX = [0,0,0,0, 1,1,1,1,1, 2, 3]
    float m0 = fmaxf(fmaxf(s[0], s[1]), fmaxf(s[2], s[3]));
    float m1 = fmaxf(fmaxf(fmaxf(s[4], s[5]), s[6]), fmaxf(s[7], s[8]));
    float m2 = s[9], m3 = s[10];
    idx = 0; float best = m0;
    if (m1 > best) { best = m1; idx = 1; }
    if (m2 > best) { best = m2; idx = 2; }
    if (m3 > best) { best = m3; idx = 3; }
    float second = -3.4e38f;
    if (idx != 0) second = fmaxf(second, m0);
    if (idx != 1) second = fmaxf(second, m1);
    if (idx != 2) second = fmaxf(second, m2);
    if (idx != 3) second = fmaxf(second, m3);
    gap = best - second;
}

__global__ __launch_bounds__(128) void decode(const float* __restrict__ X,
                                              float* __restrict__ out, int B) {
    __shared__ float xbuf[2][128][LROW];  // 36864 B, wave-private halves
    __shared__ float w_lds[704];          // 2816 B; total 39680 -> 4 blk/CU

    const int tid = threadIdx.x;
    const int lane = tid & 63;
    const int wv = tid >> 6;
    float(*buf)[LROW] = xbuf[wv];

    // Copy W into LDS: 176 float4s over 128 threads.
    for (int t = tid; t < 176; t += 128)
        reinterpret_cast<float4*>(w_lds)[t] =
            reinterpret_cast<const float4*>(g_W32)[t];
    __syncthreads();  // only block-wide sync; rest is wave-private

    const float4* X4 = reinterpret_cast<const float4*>(X);
    const int gwave = blockIdx.x * 2 + wv;
    const int nwaves = gridDim.x * 2;

    #pragma unroll 1
    for (int base = gwave * 128; base < B; base += nwaves * 128) {
        float acc0[NP], acc1[NP];
        #pragma unroll
        for (int p = 0; p < NP; ++p) { acc0[p] = 0.0f; acc1[p] = 0.0f; }

        #pragma unroll
        for (int st = 0; st < 2; ++st) {  // d half: st*32 .. st*32+31
            // Stage 128 rows x 32 floats; instr i covers 8 FULL 128B lines
            // (8 lanes/row x 16 B contiguous).
            #pragma unroll
            for (int i = 0; i < 16; ++i) {
                int fid = i * 64 + lane;  // 0..1023
                int row = fid >> 3;       // 0..127
                int f = fid & 7;          // 0..7
                int r = base + row;
                if (r >= B) r = B - 1;    // tail clamp (dup read, harmless)
                float4 v = X4[(size_t)r * 16 + st * 8 + f];
                *reinterpret_cast<float4*>(&buf[row][f * 4]) = v;
            }
            __builtin_amdgcn_wave_barrier();  // wave-private buf: fence only

            // Per 4-d chunk: 2 lane b128 (X rows) + 11 uniform b128 (W
            // quads) + 88 v_fma_f32. unroll 1: W never bulk-hoisted (r2).
            #pragma unroll 1
            for (int kk = 0; kk < 8; ++kk) {
                const float* wrow = &w_lds[(st * 8 + kk) * 44];
                float4 x0 = *reinterpret_cast<const float4*>(&buf[lane][kk * 4]);
                float4 x1 = *reinterpret_cast<const float4*>(&buf[lane + 64][kk * 4]);
                #pragma unroll
                for (int p = 0; p < NP; ++p) {
                    float4 wq = *reinterpret_cast<const float4*>(&wrow[p * 4]);
                    float t0 = fmaf(x0.x, wq.x, acc0[p]);
                    t0 = fmaf(x0.y, wq.y, t0);
                    t0 = fmaf(x0.z, wq.z, t0);
                    acc0[p] = fmaf(x0.w, wq.w, t0);
                    float t1 = fmaf(x1.x, wq.x, acc1[p]);
                    t1 = fmaf(x1.y, wq.y, t1);
                    t1 = fmaf(x1.z, wq.z, t1);
                    acc1[p] = fmaf(x1.w, wq.w, t1);
                }
            }
            __builtin_amdgcn_wave_barrier();
        }

        int idx0, idx1; float gap0, gap1;
        argmax_gap(acc0, idx0, gap0);
        argmax_gap(acc1, idx1, gap1);

        unsigned long long m0 = __ballot(gap0 < TAU);
        unsigned long long m1 = __ballot(gap1 < TAU);
        if (lane == 0) {
            g_bits[(base >> 6) + 0] = m0;
            g_bits[(base >> 6) + 1] = m1;
        }

        int r0 = base + lane, r1 = base + 64 + lane;
        if (r0 < B) {
            float4 o;
            o.x = (idx0 == 0) ? 1.0f : 0.0f;
            o.y = (idx0 == 1) ? 1.0f : 0.0f;
            o.z = (idx0 == 2) ? 1.0f : 0.0f;
            o.w = (idx0 == 3) ? 1.0f : 0.0f;
            reinterpret_cast<float4*>(out)[r0] = o;
        }
        if (r1 < B) {
            float4 o;
            o.x = (idx1 == 0) ? 1.0f : 0.0f;
            o.y = (idx1 == 1) ? 1.0f : 0.0f;
            o.z = (idx1 == 2) ? 1.0f : 0.0f;
            o.w = (idx1 == 3) ? 1.0f : 0.0f;
            reinterpret_cast<float4*>(out)[r1] = o;
        }
    }
}

__global__ __launch_bounds__(256) void repair(const float* __restrict__ X,
                                              float* __restrict__ out, int B) {
    __shared__ double w64[704];  // copy of g_W64
    const int tid = threadIdx.x;
    for (int i = tid; i < 704; i += 256) w64[i] = g_W64[i];
    __syncthreads();

    const int nwords = (B + 63) >> 6;
    for (int t = blockIdx.x * blockDim.x + tid; t < nwords;
         t += gridDim.x * blockDim.x) {
        unsigned long long m = g_bits[t];
        while (m) {
            int b = __builtin_ctzll(m);
            m &= m - 1;
            int row = t * 64 + b;
            if (row >= B) continue;

            double s[NP];
            #pragma unroll
            for (int p = 0; p < NP; ++p) s[p] = 0.0;
            #pragma unroll 1
            for (int d = 0; d < 64; ++d) {
                double x = (double)X[(size_t)row * 64 + d];
                #pragma unroll
                for (int p = 0; p < NP; ++p)
                    s[p] = fma(x, w64[d * NP + p], s[p]);
            }

            double m0 = fmax(fmax(s[0], s[1]), fmax(s[2], s[3]));
            double m1 = fmax(fmax(fmax(s[4], s[5]), s[6]), fmax(s[7], s[8]));
            double m2 = s[9], m3 = s[10];
            int idx = 0; double best = m0;
            if (m1 > best) { best = m1; idx = 1; }
            if (m2 > best) { best = m2; idx = 2; }
            if (m3 > best) { best = m3; idx = 3; }

            float4 o;
            o.x = (idx == 0) ? 1.0f : 0.0f;
            o.y = (idx == 1) ? 1.0f : 0.0f;
            o.z = (idx == 2) ? 1.0f : 0.0f;
            o.w = (idx == 3) ? 1.0f : 0.0f;
            reinterpret_cast<float4*>(out)[row] = o;
        }
    }
}

extern "C" void kernel_launch(void* const* d_in, const int* in_sizes, int n_in,
                              void* d_out, int out_size, void* d_ws, size_t ws_size,
                              hipStream_t stream) {
    const float* X = (const float*)d_in[0];
    const float* A = (const float*)d_in[1];
    float* out = (float*)d_out;
    const int B = in_sizes[0] / 64;

    hipLaunchKernelGGL(prep, dim3(1), dim3(64), 0, stream, A);
    hipLaunchKernelGGL(decode, dim3(1024), dim3(128), 0, stream, X, out, B);
    hipLaunchKernelGGL(repair, dim3(128), dim3(256), 0, stream, X, out, B);
}